// Round 8
// baseline (146.031 us; speedup 1.0000x reference)
//
#include <hip/hip_runtime.h>
#include <stdint.h>

// CRF mean-NLL, B=1024 S=1024 T=16.
// logZ via exp-domain linear recurrence: u_t = N_t u_{t-1}, N_t = diag(x_t)*E, E[m][k]=exp(trans[k][m]).
// fused1: each wave computes TWO chunks (c and c+8) as two independent full 64-step chains
//   (P <- (diag(x_t)E)P; lane needs only scalar x_t[m], staged TRANSPOSED in wave-private LDS,
//   one ds_read_b128 per 4 steps per chain). Rescale is DEFERRED: wave-uniform power-of-2
//   exponent measured at boundary k is applied at boundary k+1, keeping the two dependent
//   ds_swizzles out of the MFMA chain (headroom: worst 4-step growth 2^46, window 2^92 < 2^127).
//   blocks [0,2048) = phase1; blocks [2048,3072) = gold score (+ d_out zeroing).
// combine: 1 wave/batch, 15 sequential MFMA products over chunk mats w/ exact scale algebra.

#define BB 1024
#define SS 1024
#define TT 16
#define CC 16
#define LL 64
#define XS 68               // padded LDS row stride (floats): 2-way bank alias only (free)
#define P1B (BB * CC / 8)   // 2048 phase1 blocks (4 waves x 2 chunks each)

typedef float    f32x4 __attribute__((ext_vector_type(4)));
typedef float    f32x2 __attribute__((ext_vector_type(2)));
typedef int      i32x4 __attribute__((ext_vector_type(4)));
typedef short    s16x4 __attribute__((ext_vector_type(4)));
typedef uint32_t u32x2 __attribute__((ext_vector_type(2)));

// truncating f32->bf16 pack of (lo,hi) into one dword: single v_perm_b32
__device__ __forceinline__ uint32_t pkt(float lo, float hi) {
    return __builtin_amdgcn_perm(__float_as_uint(hi), __float_as_uint(lo), 0x07060302u);
}
__device__ __forceinline__ s16x4 mk_frag(uint32_t lo, uint32_t hi) {
    u32x2 t; t.x = lo; t.y = hi;
    return __builtin_bit_cast(s16x4, t);
}

__global__ __launch_bounds__(256) void fused1_kernel(
        const float* __restrict__ em,      // (B,S,T)
        const float* __restrict__ trans,   // (T,T)
        const int*   __restrict__ tags,    // (B,S) int32
        const float* __restrict__ startt,  // (T)
        const float* __restrict__ endt,    // (T)
        float* __restrict__ mats,          // (B*C,256)
        int*   __restrict__ scales,        // (B*C,16)
        float* __restrict__ gold,          // (B)
        float* __restrict__ out)           // zeroed here (gold branch)
{
    __shared__ float xbuf[4][2][TT * XS];  // 8.5KB per wave, wave-private (no __syncthreads)
    __shared__ float red[256];
    if (blockIdx.x < P1B) {
        // ---------------- phase 1: two chunks per wave ----------------
        const int wave = threadIdx.x >> 6;
        const int lane = threadIdx.x & 63;
        const int pid  = blockIdx.x * 4 + wave;   // 0 .. 8191
        const int b    = pid >> 3;
        const int cp   = pid & 7;                 // chunk pair: (cp, cp+8)
        const int q    = lane >> 4;
        const int m    = lane & 15;

        // constant E rows (truncation-compensated): e_j = exp(trans[4q+j][m]) * comp
        const float comp = 1.00390625f;    // (1+2^-9)^2
        f32x2 e01, e23;
        e01.x = __expf(trans[(4*q + 0) * TT + m]) * comp;
        e01.y = __expf(trans[(4*q + 1) * TT + m]) * comp;
        e23.x = __expf(trans[(4*q + 2) * TT + m]) * comp;
        e23.y = __expf(trans[(4*q + 3) * TT + m]) * comp;

        // stage exp(em) TRANSPOSED for both chunks: x[state][t] at xb[state*XS + t]
        const float* ep0 = em + (size_t)b * SS * TT + (size_t)cp * LL * TT + lane;
        const float* ep1 = ep0 + 8 * LL * TT;
        float* xb0 = xbuf[wave][0];
        float* xb1 = xbuf[wave][1];
        {
            float v0[16], v1[16];
            #pragma unroll
            for (int k = 0; k < 16; ++k) v0[k] = ep0[k * 64];   // em[64c+4k+q][m]
            #pragma unroll
            for (int k = 0; k < 16; ++k) v1[k] = ep1[k * 64];
            #pragma unroll
            for (int k = 0; k < 16; ++k) xb0[m * XS + 4 * k + q] = __expf(v0[k]);
            #pragma unroll
            for (int k = 0; k < 16; ++k) xb1[m * XS + 4 * k + q] = __expf(v1[k]);
        }

        // two independent full-chunk chains, D layout, identity start
        f32x4 sd0, sd1;
        sd0[0] = sd1[0] = (4*q + 0 == m) ? 1.f : 0.f;
        sd0[1] = sd1[1] = (4*q + 1 == m) ? 1.f : 0.f;
        sd0[2] = sd1[2] = (4*q + 2 == m) ? 1.f : 0.f;
        sd0[3] = sd1[3] = (4*q + 3 == m) ? 1.f : 0.f;
        const f32x4 zero = {0.f, 0.f, 0.f, 0.f};
        int sc0 = 0, sc1 = 0;          // applied exponent accumulators
        int pe0 = 0, pe1 = 0;          // pending exponents (deferred one boundary)
        const bool skip0 = (cp == 0);  // chunk 0 covers t=1..63

#define STEP(sd, xm) {                                                      \
        f32x2 xx; xx.x = (xm); xx.y = (xm);                                 \
        const f32x2 a01 = xx * e01;                                         \
        const f32x2 a23 = xx * e23;                                         \
        const s16x4 afr = mk_frag(pkt(a01.x, a01.y), pkt(a23.x, a23.y));    \
        const s16x4 bfr = mk_frag(pkt(sd[0], sd[1]), pkt(sd[2], sd[3]));    \
        sd = __builtin_amdgcn_mfma_f32_16x16x16bf16_1k(afr, bfr, zero, 0, 0, 0); }

        // deferred boundary: apply last boundary's exponent, then measure a new one
        // (the two dependent ds_swizzles resolve during the NEXT 4 MFMA steps)
#define BOUND(sd, sc, pe) {                                                 \
        const float sf_ = __uint_as_float((uint32_t)(127 - pe) << 23);      \
        sd[0] *= sf_; sd[1] *= sf_; sd[2] *= sf_; sd[3] *= sf_;             \
        sc += pe;                                                           \
        float mx = fmaxf(fmaxf(sd[0], sd[1]), fmaxf(sd[2], sd[3]));         \
        mx = fmaxf(mx, __shfl_xor(mx, 16, 64));                             \
        mx = fmaxf(mx, __shfl_xor(mx, 32, 64));                             \
        pe = (int)(__float_as_uint(mx) >> 23) - 127; }

        const float* xr0 = xb0 + m * XS;
        const float* xr1 = xb1 + m * XS;
        f32x4 cx0 = *(const f32x4*)(xr0);
        f32x4 cx1 = *(const f32x4*)(xr1);

        #pragma unroll
        for (int g = 0; g < 16; ++g) {            // 16 groups of 4 steps per chain
            f32x4 nx0, nx1;
            if (g < 15) {
                nx0 = *(const f32x4*)(xr0 + 4 * (g + 1));
                nx1 = *(const f32x4*)(xr1 + 4 * (g + 1));
            }
            #pragma unroll
            for (int i = 0; i < 4; ++i) {
                if (!(skip0 && g == 0 && i == 0)) STEP(sd0, cx0[i]);
                STEP(sd1, cx1[i]);
            }
            BOUND(sd0, sc0, pe0);
            BOUND(sd1, sc1, pe1);
            cx0 = nx0; cx1 = nx1;
        }
#undef STEP
#undef BOUND

        // store both chunk products (sc excludes the still-pending exponent - consistent)
        const int id0 = b * CC + cp;
        const int id1 = id0 + 8;
        float* mp0 = mats + (size_t)id0 * 256;
        float* mp1 = mats + (size_t)id1 * 256;
        mp0[(4*q + 0) * TT + m] = sd0[0];
        mp0[(4*q + 1) * TT + m] = sd0[1];
        mp0[(4*q + 2) * TT + m] = sd0[2];
        mp0[(4*q + 3) * TT + m] = sd0[3];
        mp1[(4*q + 0) * TT + m] = sd1[0];
        mp1[(4*q + 1) * TT + m] = sd1[1];
        mp1[(4*q + 2) * TT + m] = sd1[2];
        mp1[(4*q + 3) * TT + m] = sd1[3];
        if (q == 0) {
            scales[id0 * 16 + m] = sc0;    // wave-uniform, stored per-column for combine
            scales[id1 * 16 + m] = sc1;
        }
    } else {
        // ---------------- gold score ----------------
        const int b = blockIdx.x - P1B, tid = threadIdx.x;
        if (b == 0 && tid == 0) out[0] = 0.f;     // replaces hipMemsetAsync
        float local = 0.f;
        for (int t = tid; t < SS; t += 256) {
            const int tg = tags[b * SS + t];
            float v = em[(size_t)(b * SS + t) * TT + tg];
            if (t > 0) v += trans[tg * TT + tags[b * SS + t - 1]];  // trans[next, prev]
            else       v += startt[tg];
            if (t == SS - 1) v += endt[tg];                          // mask all-true
            local += v;
        }
        red[tid] = local; __syncthreads();
        for (int s = 128; s > 0; s >>= 1) { if (tid < s) red[tid] += red[tid + s]; __syncthreads(); }
        if (tid == 0) gold[b] = red[0];
    }
}

// ---------------- combine: MFMA chunk-product + epilogue + final reduce ----------------
__global__ __launch_bounds__(256) void combine_kernel(
        const float* __restrict__ em,
        const float* __restrict__ startt,
        const float* __restrict__ endt,
        const float* __restrict__ mats,
        const int*   __restrict__ scales,
        const float* __restrict__ gold,
        float* __restrict__ out)
{
    const int wave = threadIdx.x >> 6;
    const int lane = threadIdx.x & 63;
    const int b    = blockIdx.x * 4 + wave;   // one wave per batch
    const int q    = lane >> 4;
    const int m    = lane & 15;

    const float* m0 = mats + (size_t)(b * CC) * 256;
    f32x4 d;
    d[0] = m0[(4*q + 0) * TT + m];
    d[1] = m0[(4*q + 1) * TT + m];
    d[2] = m0[(4*q + 2) * TT + m];
    d[3] = m0[(4*q + 3) * TT + m];
    int sig = scales[(b * CC) * 16 + m];
    int gam = 0;
    const f32x4 zero = {0.f, 0.f, 0.f, 0.f};

    #pragma unroll 4
    for (int c = 1; c < CC; ++c) {
        const int idc = b * CC + c;
        const f32x4 a = *(const f32x4*)(mats + (size_t)idc * 256 + m * TT + 4 * q);
        const i32x4 s = *(const i32x4*)(scales + idc * 16 + 4 * q);
        int sm = max(max(s.x, s.y), max(s.z, s.w));
        sm = max(sm, __shfl_xor(sm, 16, 64));
        sm = max(sm, __shfl_xor(sm, 32, 64));
        const float r0 = ldexpf(d[0], s.x - sm);
        const float r1 = ldexpf(d[1], s.y - sm);
        const float r2 = ldexpf(d[2], s.z - sm);
        const float r3 = ldexpf(d[3], s.w - sm);
        const s16x4 bfr = mk_frag(pkt(r0, r1), pkt(r2, r3));
        const s16x4 afr = mk_frag(pkt(a.x, a.y), pkt(a.z, a.w));
        d = __builtin_amdgcn_mfma_f32_16x16x16bf16_1k(afr, bfr, zero, 0, 0, 0);
        gam += sm;
        float mx = fmaxf(fmaxf(d[0], d[1]), fmaxf(d[2], d[3]));
        mx = fmaxf(mx, __shfl_xor(mx, 16, 64));
        mx = fmaxf(mx, __shfl_xor(mx, 32, 64));
        const int e = (int)(__float_as_uint(mx) >> 23) - 127;
        const float sf = __uint_as_float((uint32_t)(127 - e) << 23);
        d[0] *= sf; d[1] *= sf; d[2] *= sf; d[3] *= sf;
        sig += e;
    }

    // ---- epilogue: logZ = mx0 + ln2*(gam + sigmax) + log( end^T * V * w ) ----
    const float s0 = startt[m] + em[(size_t)b * SS * TT + m];
    float mx0 = s0;
    #pragma unroll
    for (int s = 1; s < 16; s <<= 1) mx0 = fmaxf(mx0, __shfl_xor(mx0, s, 64));
    const float u0n = __expf(s0 - mx0);

    int sigmax = sig;
    #pragma unroll
    for (int s = 1; s < 16; s <<= 1) sigmax = max(sigmax, __shfl_xor(sigmax, s, 64));
    const float w = ldexpf(u0n, sig - sigmax);

    f32x4 v;
    v[0] = d[0] * w; v[1] = d[1] * w; v[2] = d[2] * w; v[3] = d[3] * w;
    #pragma unroll
    for (int s = 1; s < 16; s <<= 1) {
        v[0] += __shfl_xor(v[0], s, 64);
        v[1] += __shfl_xor(v[1], s, 64);
        v[2] += __shfl_xor(v[2], s, 64);
        v[3] += __shfl_xor(v[3], s, 64);
    }
    const f32x4 ee = *(const f32x4*)(endt + 4 * q);
    float z = __expf(ee.x) * v[0] + __expf(ee.y) * v[1]
            + __expf(ee.z) * v[2] + __expf(ee.w) * v[3];
    z += __shfl_xor(z, 16, 64);
    z += __shfl_xor(z, 32, 64);

    if (lane == 0) {
        const float logZ = mx0 + 0.69314718055994531f * (float)(gam + sigmax) + __logf(z);
        atomicAdd(out, (logZ - gold[b]) * (1.0f / BB));
    }
}

extern "C" void kernel_launch(void* const* d_in, const int* in_sizes, int n_in,
                              void* d_out, int out_size, void* d_ws, size_t ws_size,
                              hipStream_t stream) {
    const float* em     = (const float*)d_in[0];   // (B,S,T) fp32
    const int*   tags   = (const int*)  d_in[1];   // (B,S) int32
    // d_in[2] = mask, all ones -> ignored
    const float* trans  = (const float*)d_in[3];   // (T,T)
    const float* startt = (const float*)d_in[4];   // (T,)
    const float* endt   = (const float*)d_in[5];   // (T,)
    float* out = (float*)d_out;

    float* mats   = (float*)d_ws;                                          // 16 MB
    int*   scales = (int*)((char*)d_ws + (size_t)BB * CC * 256 * 4);       // 1 MB
    float* gold   = (float*)((char*)scales + (size_t)BB * CC * 16 * 4);    // 4 KB

    fused1_kernel<<<P1B + BB, 256, 0, stream>>>(em, trans, tags, startt, endt, mats, scales, gold, out);
    combine_kernel<<<BB / 4, 256, 0, stream>>>(em, startt, endt, mats, scales, gold, out);
}

// Round 10
// 140.395 us; speedup vs baseline: 1.0401x; 1.0401x over previous
//
#include <hip/hip_runtime.h>
#include <stdint.h>

// CRF mean-NLL, B=1024 S=1024 T=16.
// logZ via exp-domain linear recurrence: u_t = N_t u_{t-1}, N_t = diag(x_t)*E, E[m][k]=exp(trans[k][m]).
// fused1 (R7 skeleton + ROLLED hot loop): per wave one 64-step chunk as two independent 32-step
//   half-chains. STEP is the A-SIDE form (matches the transposed staging!): lane (q,m) scales
//   E's row by the SCALAR x_t[m] -> afr; running product enters as B. exp(em) staged TRANSPOSED
//   in wave-private LDS (x[state][t], stride 68); one ds_read_b128 per 4 steps per chain.
//   DEFERRED per-column power-of-2 rescale per 4-step group (exponent measured at boundary k is
//   applied at k+1 -> the two dependent ds_swizzles stay off the MFMA chain; headroom 2^96).
//   Main loop is ROLLED (~700B body) to test the L0 i-cache theory. In-wave merge P = Phi*Plo
//   via one extra MFMA with exact scale algebra.
//   blocks [0,4096) = phase1; blocks [4096,5120) = gold score (+ d_out zeroing).
// combine: 1 wave/batch, 15 sequential MFMA products over chunk mats w/ exact scale algebra.

#define BB 1024
#define SS 1024
#define TT 16
#define CC 16
#define LL 64
#define XS 68               // padded LDS row stride (floats): 2-way bank alias only (free)
#define P1B (BB * CC / 4)   // 4096 phase1 blocks

typedef float    f32x4 __attribute__((ext_vector_type(4)));
typedef float    f32x2 __attribute__((ext_vector_type(2)));
typedef int      i32x4 __attribute__((ext_vector_type(4)));
typedef short    s16x4 __attribute__((ext_vector_type(4)));
typedef uint32_t u32x2 __attribute__((ext_vector_type(2)));

// truncating f32->bf16 pack of (lo,hi) into one dword: single v_perm_b32
__device__ __forceinline__ uint32_t pkt(float lo, float hi) {
    return __builtin_amdgcn_perm(__float_as_uint(hi), __float_as_uint(lo), 0x07060302u);
}
__device__ __forceinline__ s16x4 mk_frag(uint32_t lo, uint32_t hi) {
    u32x2 t; t.x = lo; t.y = hi;
    return __builtin_bit_cast(s16x4, t);
}

__global__ __launch_bounds__(256, 4) void fused1_kernel(
        const float* __restrict__ em,      // (B,S,T)
        const float* __restrict__ trans,   // (T,T)
        const int*   __restrict__ tags,    // (B,S) int32
        const float* __restrict__ startt,  // (T)
        const float* __restrict__ endt,    // (T)
        float* __restrict__ mats,          // (B*C,256)
        int*   __restrict__ scales,        // (B*C,16)
        float* __restrict__ gold,          // (B)
        float* __restrict__ out)           // zeroed here (gold branch)
{
    __shared__ float xbuf[4][TT * XS];     // 4.25KB per wave, wave-private (no __syncthreads)
    __shared__ int   sbuf[4][16];
    __shared__ float red[256];
    if (blockIdx.x < P1B) {
        // ---------------- phase 1 ----------------
        const int wave = threadIdx.x >> 6;
        const int lane = threadIdx.x & 63;
        const int id   = blockIdx.x * 4 + wave;   // (b,c)
        const int b    = id >> 4;
        const int c    = id & 15;
        const int q    = lane >> 4;
        const int m    = lane & 15;

        // constant E rows (truncation-compensated): e_j = exp(trans[4q+j][m]) * comp
        const float comp = 1.00390625f;    // (1+2^-9)^2: per-step A trunc + B trunc
        f32x2 e01, e23;
        e01.x = __expf(trans[(4*q + 0) * TT + m]) * comp;
        e01.y = __expf(trans[(4*q + 1) * TT + m]) * comp;
        e23.x = __expf(trans[(4*q + 2) * TT + m]) * comp;
        e23.y = __expf(trans[(4*q + 3) * TT + m]) * comp;

        // stage exp(em) TRANSPOSED: x[state][t] at xb[state*XS + t]
        const float* ep = em + (size_t)b * SS * TT + (size_t)c * LL * TT + lane;
        float* xb = xbuf[wave];
        {
            float v[16];
            #pragma unroll
            for (int k = 0; k < 16; ++k) v[k] = ep[k * 64];     // em[64c+4k+q][m]
            #pragma unroll
            for (int k = 0; k < 16; ++k) xb[m * XS + 4 * k + q] = __expf(v[k]);
        }

        // two independent half-chains, D layout, identity start
        f32x4 sd0, sd1;
        sd0[0] = sd1[0] = (4*q + 0 == m) ? 1.f : 0.f;
        sd0[1] = sd1[1] = (4*q + 1 == m) ? 1.f : 0.f;
        sd0[2] = sd1[2] = (4*q + 2 == m) ? 1.f : 0.f;
        sd0[3] = sd1[3] = (4*q + 3 == m) ? 1.f : 0.f;
        const f32x4 zero = {0.f, 0.f, 0.f, 0.f};
        int sc0 = 0, sc1 = 0;          // applied exponent accumulators
        int pe0 = 0, pe1 = 0;          // pending exponents (deferred one boundary)
        const bool skip0 = (c == 0);   // chunk 0 covers t=1..63

        // A-SIDE step: lane (q,m) needs only the scalar x_t[m] (matches transposed staging)
#define STEP(sd, xm) {                                                      \
        f32x2 xx; xx.x = (xm); xx.y = (xm);                                 \
        const f32x2 a01_ = xx * e01;                                        \
        const f32x2 a23_ = xx * e23;                                        \
        const s16x4 afr_ = mk_frag(pkt(a01_.x, a01_.y), pkt(a23_.x, a23_.y)); \
        const s16x4 bfr_ = mk_frag(pkt(sd[0], sd[1]), pkt(sd[2], sd[3]));   \
        sd = __builtin_amdgcn_mfma_f32_16x16x16bf16_1k(afr_, bfr_, zero, 0, 0, 0); }

        // deferred boundary: apply last boundary's exponent, then measure a new one
#define BOUND(sd, sc, pe) {                                                 \
        const float sf_ = __uint_as_float((uint32_t)(127 - pe) << 23);      \
        sd[0] *= sf_; sd[1] *= sf_; sd[2] *= sf_; sd[3] *= sf_;             \
        sc += pe;                                                           \
        float mx = fmaxf(fmaxf(sd[0], sd[1]), fmaxf(sd[2], sd[3]));         \
        mx = fmaxf(mx, __shfl_xor(mx, 16, 64));                             \
        mx = fmaxf(mx, __shfl_xor(mx, 32, 64));                             \
        pe = (int)(__float_as_uint(mx) >> 23) - 127; }

        const float* xr0 = xb + m * XS;        // chain0: t-local 0..31 (x[m][t])
        const float* xr1 = xr0 + 32;           // chain1: t-local 32..63
        f32x4 cx0 = *(const f32x4*)(xr0);
        f32x4 cx1 = *(const f32x4*)(xr1);

        // ---- peeled group 0 (handles the chunk-0 skip of step t=0) ----
        {
            const f32x4 nx0 = *(const f32x4*)(xr0 + 4);
            const f32x4 nx1 = *(const f32x4*)(xr1 + 4);
            if (!skip0) STEP(sd0, cx0[0]);
            STEP(sd1, cx1[0]);
            STEP(sd0, cx0[1]); STEP(sd1, cx1[1]);
            STEP(sd0, cx0[2]); STEP(sd1, cx1[2]);
            STEP(sd0, cx0[3]); STEP(sd1, cx1[3]);
            BOUND(sd0, sc0, pe0);
            BOUND(sd1, sc1, pe1);
            cx0 = nx0; cx1 = nx1;
        }

        // ---- rolled main loop: small body, stays in L0 i-cache ----
        #pragma clang loop unroll(disable)
        for (int g = 1; g < 8; ++g) {
            const f32x4 nx0 = *(const f32x4*)(xr0 + 4 * ((g + 1) & 7));  // wraps harmlessly at g=7
            const f32x4 nx1 = *(const f32x4*)(xr1 + 4 * ((g + 1) & 7));
            STEP(sd0, cx0[0]); STEP(sd1, cx1[0]);
            STEP(sd0, cx0[1]); STEP(sd1, cx1[1]);
            STEP(sd0, cx0[2]); STEP(sd1, cx1[2]);
            STEP(sd0, cx0[3]); STEP(sd1, cx1[3]);
            BOUND(sd0, sc0, pe0);
            BOUND(sd1, sc1, pe1);
            cx0 = nx0; cx1 = nx1;
        }

        // fold the still-pending exponents so sc matches sd exactly
        {
            const float f0 = __uint_as_float((uint32_t)(127 - pe0) << 23);
            sd0[0] *= f0; sd0[1] *= f0; sd0[2] *= f0; sd0[3] *= f0; sc0 += pe0;
            const float f1 = __uint_as_float((uint32_t)(127 - pe1) << 23);
            sd1[0] *= f1; sd1[1] *= f1; sd1[2] *= f1; sd1[3] *= f1; sc1 += pe1;
        }

        // ---- in-wave merge: P = Phi(sd1) * Plo(sd0), exact scale algebra ----
        xb[(4*q + 0) * TT + m] = sd1[0];
        xb[(4*q + 1) * TT + m] = sd1[1];
        xb[(4*q + 2) * TT + m] = sd1[2];
        xb[(4*q + 3) * TT + m] = sd1[3];
        if (q == 0) sbuf[wave][m] = sc1;
        const f32x4 at  = *(const f32x4*)(xb + m * TT + 4 * q);   // Phi[m][4q+j]
        const i32x4 sh  = *(const i32x4*)(sbuf[wave] + 4 * q);    // shi[4q+j]
        int shimax = sc1;
        #pragma unroll
        for (int s = 1; s < 16; s <<= 1) shimax = max(shimax, __shfl_xor(shimax, s, 64));
        const float r0 = ldexpf(sd0[0], sh.x - shimax);
        const float r1 = ldexpf(sd0[1], sh.y - shimax);
        const float r2 = ldexpf(sd0[2], sh.z - shimax);
        const float r3 = ldexpf(sd0[3], sh.w - shimax);
        const s16x4 bfm = mk_frag(pkt(r0, r1), pkt(r2, r3));
        const s16x4 afm = mk_frag(pkt(at.x, at.y), pkt(at.z, at.w));
        f32x4 sd = __builtin_amdgcn_mfma_f32_16x16x16bf16_1k(afm, bfm, zero, 0, 0, 0);
        int sc = sc0 + shimax;
        // final normalize (immediate)
        {
            float mx = fmaxf(fmaxf(sd[0], sd[1]), fmaxf(sd[2], sd[3]));
            mx = fmaxf(mx, __shfl_xor(mx, 16, 64));
            mx = fmaxf(mx, __shfl_xor(mx, 32, 64));
            const int e = (int)(__float_as_uint(mx) >> 23) - 127;
            const float sf = __uint_as_float((uint32_t)(127 - e) << 23);
            sd[0] *= sf; sd[1] *= sf; sd[2] *= sf; sd[3] *= sf;
            sc += e;
        }
#undef STEP
#undef BOUND

        float* mp = mats + (size_t)id * 256;
        mp[(4*q + 0) * TT + m] = sd[0];
        mp[(4*q + 1) * TT + m] = sd[1];
        mp[(4*q + 2) * TT + m] = sd[2];
        mp[(4*q + 3) * TT + m] = sd[3];
        if (q == 0) scales[id * 16 + m] = sc;     // per-column exponent
    } else {
        // ---------------- gold score ----------------
        const int b = blockIdx.x - P1B, tid = threadIdx.x;
        if (b == 0 && tid == 0) out[0] = 0.f;     // replaces hipMemsetAsync
        float local = 0.f;
        for (int t = tid; t < SS; t += 256) {
            const int tg = tags[b * SS + t];
            float v = em[(size_t)(b * SS + t) * TT + tg];
            if (t > 0) v += trans[tg * TT + tags[b * SS + t - 1]];  // trans[next, prev]
            else       v += startt[tg];
            if (t == SS - 1) v += endt[tg];                          // mask all-true
            local += v;
        }
        red[tid] = local; __syncthreads();
        for (int s = 128; s > 0; s >>= 1) { if (tid < s) red[tid] += red[tid + s]; __syncthreads(); }
        if (tid == 0) gold[b] = red[0];
    }
}

// ---------------- combine: MFMA chunk-product + epilogue + final reduce ----------------
__global__ __launch_bounds__(256) void combine_kernel(
        const float* __restrict__ em,
        const float* __restrict__ startt,
        const float* __restrict__ endt,
        const float* __restrict__ mats,
        const int*   __restrict__ scales,
        const float* __restrict__ gold,
        float* __restrict__ out)
{
    const int wave = threadIdx.x >> 6;
    const int lane = threadIdx.x & 63;
    const int b    = blockIdx.x * 4 + wave;   // one wave per batch
    const int q    = lane >> 4;
    const int m    = lane & 15;

    const float* m0 = mats + (size_t)(b * CC) * 256;
    f32x4 d;
    d[0] = m0[(4*q + 0) * TT + m];
    d[1] = m0[(4*q + 1) * TT + m];
    d[2] = m0[(4*q + 2) * TT + m];
    d[3] = m0[(4*q + 3) * TT + m];
    int sig = scales[(b * CC) * 16 + m];
    int gam = 0;
    const f32x4 zero = {0.f, 0.f, 0.f, 0.f};

    #pragma unroll 4
    for (int c = 1; c < CC; ++c) {
        const int idc = b * CC + c;
        const f32x4 a = *(const f32x4*)(mats + (size_t)idc * 256 + m * TT + 4 * q);
        const i32x4 s = *(const i32x4*)(scales + idc * 16 + 4 * q);
        int sm = max(max(s.x, s.y), max(s.z, s.w));
        sm = max(sm, __shfl_xor(sm, 16, 64));
        sm = max(sm, __shfl_xor(sm, 32, 64));
        const float r0 = ldexpf(d[0], s.x - sm);
        const float r1 = ldexpf(d[1], s.y - sm);
        const float r2 = ldexpf(d[2], s.z - sm);
        const float r3 = ldexpf(d[3], s.w - sm);
        const s16x4 bfr = mk_frag(pkt(r0, r1), pkt(r2, r3));
        const s16x4 afr = mk_frag(pkt(a.x, a.y), pkt(a.z, a.w));
        d = __builtin_amdgcn_mfma_f32_16x16x16bf16_1k(afr, bfr, zero, 0, 0, 0);
        gam += sm;
        float mx = fmaxf(fmaxf(d[0], d[1]), fmaxf(d[2], d[3]));
        mx = fmaxf(mx, __shfl_xor(mx, 16, 64));
        mx = fmaxf(mx, __shfl_xor(mx, 32, 64));
        const int e = (int)(__float_as_uint(mx) >> 23) - 127;
        const float sf = __uint_as_float((uint32_t)(127 - e) << 23);
        d[0] *= sf; d[1] *= sf; d[2] *= sf; d[3] *= sf;
        sig += e;
    }

    // ---- epilogue: logZ = mx0 + ln2*(gam + sigmax) + log( end^T * V * w ) ----
    const float s0 = startt[m] + em[(size_t)b * SS * TT + m];
    float mx0 = s0;
    #pragma unroll
    for (int s = 1; s < 16; s <<= 1) mx0 = fmaxf(mx0, __shfl_xor(mx0, s, 64));
    const float u0n = __expf(s0 - mx0);

    int sigmax = sig;
    #pragma unroll
    for (int s = 1; s < 16; s <<= 1) sigmax = max(sigmax, __shfl_xor(sigmax, s, 64));
    const float w = ldexpf(u0n, sig - sigmax);

    f32x4 v;
    v[0] = d[0] * w; v[1] = d[1] * w; v[2] = d[2] * w; v[3] = d[3] * w;
    #pragma unroll
    for (int s = 1; s < 16; s <<= 1) {
        v[0] += __shfl_xor(v[0], s, 64);
        v[1] += __shfl_xor(v[1], s, 64);
        v[2] += __shfl_xor(v[2], s, 64);
        v[3] += __shfl_xor(v[3], s, 64);
    }
    const f32x4 ee = *(const f32x4*)(endt + 4 * q);
    float z = __expf(ee.x) * v[0] + __expf(ee.y) * v[1]
            + __expf(ee.z) * v[2] + __expf(ee.w) * v[3];
    z += __shfl_xor(z, 16, 64);
    z += __shfl_xor(z, 32, 64);

    if (lane == 0) {
        const float logZ = mx0 + 0.69314718055994531f * (float)(gam + sigmax) + __logf(z);
        atomicAdd(out, (logZ - gold[b]) * (1.0f / BB));
    }
}

extern "C" void kernel_launch(void* const* d_in, const int* in_sizes, int n_in,
                              void* d_out, int out_size, void* d_ws, size_t ws_size,
                              hipStream_t stream) {
    const float* em     = (const float*)d_in[0];   // (B,S,T) fp32
    const int*   tags   = (const int*)  d_in[1];   // (B,S) int32
    // d_in[2] = mask, all ones -> ignored
    const float* trans  = (const float*)d_in[3];   // (T,T)
    const float* startt = (const float*)d_in[4];   // (T,)
    const float* endt   = (const float*)d_in[5];   // (T,)
    float* out = (float*)d_out;

    float* mats   = (float*)d_ws;                                          // 16 MB
    int*   scales = (int*)((char*)d_ws + (size_t)BB * CC * 256 * 4);       // 1 MB
    float* gold   = (float*)((char*)scales + (size_t)BB * CC * 16 * 4);    // 4 KB

    fused1_kernel<<<P1B + BB, 256, 0, stream>>>(em, trans, tags, startt, endt, mats, scales, gold, out);
    combine_kernel<<<BB / 4, 256, 0, stream>>>(em, startt, endt, mats, scales, gold, out);
}